// Round 2
// baseline (424.413 us; speedup 1.0000x reference)
//
#include <hip/hip_runtime.h>

// i1e(x) = exp(-|x|) * I1(x) * sign(x), Abramowitz & Stegun 9.8.3/9.8.4
// rational approximations, mirroring the JAX reference (fp32 Horner, same
// coefficients, branch point 3.75). Output dtype: float32.
//
// Memory-bound streaming kernel: 268 MB in + 268 MB out, no reuse.
// - nontemporal loads/stores (via clang ext_vector_type; HIP float4 is a
//   struct the builtin rejects): skip cache allocation for the pure stream
// - 8 elems/thread (2x 16B), both loads issued before compute (MLP=2)
// - large branch: 1/axl = rsqrt(axl)^2 -> reuse rsqrt, drop the v_rcp

typedef float f32x4 __attribute__((ext_vector_type(4)));

__device__ __forceinline__ float i1e_f(float x) {
    float ax = fabsf(x);

    // ---- small branch: ax <= 3.75 ----
    float ts = ax * (1.0f / 3.75f);
    ts = ts * ts;
    float ps = 0.00032411f;
    ps = ps * ts + 0.00301532f;
    ps = ps * ts + 0.02658733f;
    ps = ps * ts + 0.15084934f;
    ps = ps * ts + 0.51498869f;
    ps = ps * ts + 0.87890594f;
    ps = ps * ts + 0.5f;
    float small = ax * ps * __expf(-ax);

    // ---- large branch: ax > 3.75 ----
    float axl = fmaxf(ax, 3.75f);          // avoid div issues in unselected lane
    float rs  = rsqrtf(axl);               // 1/sqrt(axl)
    float tl  = 3.75f * rs * rs;           // 3.75/axl without a v_rcp
    float pl = -0.00420059f;
    pl = pl * tl + 0.01787654f;
    pl = pl * tl + (-0.02895312f);
    pl = pl * tl + 0.02282967f;
    pl = pl * tl + (-0.01031555f);
    pl = pl * tl + 0.00163801f;
    pl = pl * tl + (-0.00362018f);
    pl = pl * tl + (-0.03988024f);
    pl = pl * tl + 0.39894228f;
    float large = pl * rs;

    float r = (ax <= 3.75f) ? small : large;
    return (x < 0.0f) ? -r : r;            // I1 is odd; r==0 at x==0 anyway
}

__global__ __launch_bounds__(256) void i1e_kernel(const float* __restrict__ z,
                                                  float* __restrict__ out,
                                                  long long n) {
    long long i = ((long long)blockIdx.x * blockDim.x + threadIdx.x) * 8;
    if (i + 8 <= n) {
        const f32x4* p = reinterpret_cast<const f32x4*>(z + i);
        // issue both loads before any compute (2 outstanding VMEM ops)
        f32x4 a = __builtin_nontemporal_load(p);
        f32x4 b = __builtin_nontemporal_load(p + 1);

        f32x4 r0, r1;
        r0.x = i1e_f(a.x);
        r0.y = i1e_f(a.y);
        r0.z = i1e_f(a.z);
        r0.w = i1e_f(a.w);
        r1.x = i1e_f(b.x);
        r1.y = i1e_f(b.y);
        r1.z = i1e_f(b.z);
        r1.w = i1e_f(b.w);

        f32x4* q = reinterpret_cast<f32x4*>(out + i);
        __builtin_nontemporal_store(r0, q);
        __builtin_nontemporal_store(r1, q + 1);
    } else {
        for (; i < n; ++i) {               // scalar tail (empty for N = 2^26)
            out[i] = i1e_f(z[i]);
        }
    }
}

extern "C" void kernel_launch(void* const* d_in, const int* in_sizes, int n_in,
                              void* d_out, int out_size, void* d_ws, size_t ws_size,
                              hipStream_t stream) {
    const float* z = (const float*)d_in[0];
    float* out = (float*)d_out;
    long long n = (long long)in_sizes[0];

    long long chunks = (n + 7) / 8;
    int block = 256;
    long long grid = (chunks + block - 1) / block;
    i1e_kernel<<<(dim3)(unsigned)grid, block, 0, stream>>>(z, out, n);
}

// Round 3
// 418.064 us; speedup vs baseline: 1.0152x; 1.0152x over previous
//
#include <hip/hip_runtime.h>

// i1e(x) = exp(-|x|) * I1(x) * sign(x), Abramowitz & Stegun 9.8.3/9.8.4
// rational approximations, mirroring the JAX reference (fp32 Horner, same
// coefficients, branch point 3.75). Output dtype: float32.
//
// Memory-bound streaming kernel: 268 MB in + 268 MB out, no reuse.
// Floor: ~85 us at 6.3 TB/s achievable. Round-2 A/B showed nontemporal
// load/store was neutral-to-negative (plain stores write-combine fine on
// CDNA4) -> reverted. Kept: 8 elems/thread (2x float4, both loads issued
// before compute, MLP=2) and rsqrt-reuse in the large branch (no v_rcp).

__device__ __forceinline__ float i1e_f(float x) {
    float ax = fabsf(x);

    // ---- small branch: ax <= 3.75 ----
    float ts = ax * (1.0f / 3.75f);
    ts = ts * ts;
    float ps = 0.00032411f;
    ps = ps * ts + 0.00301532f;
    ps = ps * ts + 0.02658733f;
    ps = ps * ts + 0.15084934f;
    ps = ps * ts + 0.51498869f;
    ps = ps * ts + 0.87890594f;
    ps = ps * ts + 0.5f;
    float small = ax * ps * __expf(-ax);

    // ---- large branch: ax > 3.75 ----
    float axl = fmaxf(ax, 3.75f);          // avoid div issues in unselected lane
    float rs  = rsqrtf(axl);               // 1/sqrt(axl)
    float tl  = 3.75f * rs * rs;           // 3.75/axl without a v_rcp
    float pl = -0.00420059f;
    pl = pl * tl + 0.01787654f;
    pl = pl * tl + (-0.02895312f);
    pl = pl * tl + 0.02282967f;
    pl = pl * tl + (-0.01031555f);
    pl = pl * tl + 0.00163801f;
    pl = pl * tl + (-0.00362018f);
    pl = pl * tl + (-0.03988024f);
    pl = pl * tl + 0.39894228f;
    float large = pl * rs;

    float r = (ax <= 3.75f) ? small : large;
    return (x < 0.0f) ? -r : r;            // I1 is odd; r==0 at x==0 anyway
}

__global__ __launch_bounds__(256) void i1e_kernel(const float* __restrict__ z,
                                                  float* __restrict__ out,
                                                  long long n) {
    long long i = ((long long)blockIdx.x * blockDim.x + threadIdx.x) * 8;
    if (i + 8 <= n) {
        const float4* p = reinterpret_cast<const float4*>(z + i);
        // issue both loads before any compute (2 outstanding VMEM ops)
        float4 a = p[0];
        float4 b = p[1];

        float4 r0, r1;
        r0.x = i1e_f(a.x);
        r0.y = i1e_f(a.y);
        r0.z = i1e_f(a.z);
        r0.w = i1e_f(a.w);
        r1.x = i1e_f(b.x);
        r1.y = i1e_f(b.y);
        r1.z = i1e_f(b.z);
        r1.w = i1e_f(b.w);

        float4* q = reinterpret_cast<float4*>(out + i);
        q[0] = r0;
        q[1] = r1;
    } else {
        for (; i < n; ++i) {               // scalar tail (empty for N = 2^26)
            out[i] = i1e_f(z[i]);
        }
    }
}

extern "C" void kernel_launch(void* const* d_in, const int* in_sizes, int n_in,
                              void* d_out, int out_size, void* d_ws, size_t ws_size,
                              hipStream_t stream) {
    const float* z = (const float*)d_in[0];
    float* out = (float*)d_out;
    long long n = (long long)in_sizes[0];

    long long chunks = (n + 7) / 8;
    int block = 256;
    long long grid = (chunks + block - 1) / block;
    i1e_kernel<<<(dim3)(unsigned)grid, block, 0, stream>>>(z, out, n);
}